// Round 7
// baseline (238.000 us; speedup 1.0000x reference)
//
#include <hip/hip_runtime.h>
#include <hip/hip_bf16.h>

typedef __attribute__((ext_vector_type(8))) short short8;
typedef __attribute__((ext_vector_type(4))) short short4v;
typedef __attribute__((ext_vector_type(4))) float f32x4;

#define DIM    1024
#define NHEADS 16
#define HDIM   64
#define SEQ    2048
#define BATCH  4
#define ROWS   8192            // BATCH*SEQ
#define QKV_N  3072            // 3*DIM

// 0.125 * log2(e): folds attention scale AND exp->exp2 conversion into Q
#define QSCALE_LOG2E 0.18033688011112042f

__device__ __forceinline__ unsigned short f2bf(float f) {
    union { float f; unsigned u; } v; v.f = f;
    unsigned u = v.u;
    return (unsigned short)((u + 0x7fffu + ((u >> 16) & 1u)) >> 16);   // RNE
}
__device__ __forceinline__ float exp2_fast(float x) {                // v_exp_f32 = 2^x
    float r;
    asm("v_exp_f32 %0, %1" : "=v"(r) : "v"(x));
    return r;
}
// packed f32x2 -> bf16x2 (lo = a, hi = b); no builtin on gfx950 (T12)
__device__ __forceinline__ unsigned cvt_pk_bf16(float a, float b) {
    unsigned r;
    asm("v_cvt_pk_bf16_f32 %0, %1, %2" : "=v"(r) : "v"(a), "v"(b));
    return r;
}

// async global->LDS, 16B per lane; LDS dest = wave-uniform base + lane*16
__device__ __forceinline__ void gload16(const void* g, void* l) {
    __builtin_amdgcn_global_load_lds(
        (const __attribute__((address_space(1))) unsigned int*)g,
        (__attribute__((address_space(3))) unsigned int*)l, 16, 0, 0);
}

#define MFMA16(a, b, c) __builtin_amdgcn_mfma_f32_16x16x32_bf16(a, b, c, 0, 0, 0)

// ---------------------------------------------------------------------------
// convert fp32 -> bf16 (flat)
// ---------------------------------------------------------------------------
__global__ __launch_bounds__(256)
void conv_kernel(const float* __restrict__ src, unsigned short* __restrict__ dst, int n4)
{
    const int i = blockIdx.x * 256 + threadIdx.x;
    if (i >= n4) return;
    const float4 v = ((const float4*)src)[i];
    short4v o;
    o[0] = (short)f2bf(v.x); o[1] = (short)f2bf(v.y);
    o[2] = (short)f2bf(v.z); o[3] = (short)f2bf(v.w);
    ((short4v*)dst)[i] = o;
}

// ---------------------------------------------------------------------------
// transpose + convert: src [R][C] fp32 -> dst [C][R] bf16
// ---------------------------------------------------------------------------
__global__ __launch_bounds__(256)
void convT_kernel(const float* __restrict__ src, unsigned short* __restrict__ dst,
                  int R, int C)
{
    __shared__ float T[32][33];
    const int r0 = blockIdx.y * 32, c0 = blockIdx.x * 32;
    const int tc = threadIdx.x & 31, tr = threadIdx.x >> 5;   // 32 x 8
    #pragma unroll
    for (int i = 0; i < 4; ++i)
        T[tr + i * 8][tc] = src[(size_t)(r0 + tr + i * 8) * C + c0 + tc];
    __syncthreads();
    #pragma unroll
    for (int i = 0; i < 4; ++i)
        dst[(size_t)(c0 + tr + i * 8) * R + r0 + tc] = f2bf(T[tc][tr + i * 8]);
}

// ---------------------------------------------------------------------------
// bf16 MFMA GEMM (m97 structure): C[M,N] = A[M,K] @ BT[N,K]^T (+bias).
// 128x128 tile, BK=32, 256 thr = 4 waves (2x2), 4x4 16x16x32 frags per wave.
// QSCALE: multiply cols < DIM (the Q third of qkv) by 0.125*log2e.
// ---------------------------------------------------------------------------
template<bool WITH_BIAS, bool QSCALE>
__global__ __launch_bounds__(256)
void gemm_kernel(const unsigned short* __restrict__ A,   // [M][K] bf16
                 const unsigned short* __restrict__ BT,  // [N][K] bf16
                 const float* __restrict__ bias,
                 void* __restrict__ Cp, int M, int N, int K)
{
    __shared__ alignas(16) unsigned short LA[128][32];
    __shared__ alignas(16) unsigned short LB[128][32];

    const int tid  = threadIdx.x;
    const int lane = tid & 63;
    const int w    = tid >> 6;
    const int wr   = w >> 1, wc = w & 1;
    const int bm   = blockIdx.y * 128, bn = blockIdx.x * 128;
    const int r16  = lane & 15, g = lane >> 4;

    f32x4 acc[4][4] = {};

    const int srow = lane >> 2, skg = (lane & 3) * 8;

    for (int k0 = 0; k0 < K; k0 += 32) {
        #pragma unroll
        for (int c = 0; c < 2; ++c) {
            const int chunk = w * 2 + c;            // 8 chunks over 4 waves
            gload16(A  + (size_t)(bm + chunk * 16 + srow) * K + k0 + skg, &LA[chunk * 16][0]);
            gload16(BT + (size_t)(bn + chunk * 16 + srow) * K + k0 + skg, &LB[chunk * 16][0]);
        }
        __syncthreads();
        short8 af[4], bf_[4];
        #pragma unroll
        for (int i = 0; i < 4; ++i) {
            af[i]  = *(const short8*)&LA[wr * 64 + i * 16 + r16][g * 8];
            bf_[i] = *(const short8*)&LB[wc * 64 + i * 16 + r16][g * 8];
        }
        __builtin_amdgcn_s_setprio(1);
        #pragma unroll
        for (int mi = 0; mi < 4; ++mi)
            #pragma unroll
            for (int ni = 0; ni < 4; ++ni)
                acc[mi][ni] = MFMA16(af[mi], bf_[ni], acc[mi][ni]);
        __builtin_amdgcn_s_setprio(0);
        __syncthreads();
    }

    #pragma unroll
    for (int mi = 0; mi < 4; ++mi)
        #pragma unroll
        for (int ni = 0; ni < 4; ++ni) {
            const int gcol = bn + wc * 64 + ni * 16 + r16;
            #pragma unroll
            for (int j = 0; j < 4; ++j) {
                const int grow = bm + wr * 64 + mi * 16 + g * 4 + j;
                float v = acc[mi][ni][j];
                if (QSCALE && gcol < DIM) v *= QSCALE_LOG2E;
                if (WITH_BIAS)
                    ((float*)Cp)[(size_t)grow * N + gcol] = v + bias[gcol];
                else
                    ((unsigned short*)Cp)[(size_t)grow * N + gcol] = f2bf(v);
            }
        }
}

// ---------------------------------------------------------------------------
// MFMA flash attention, SWAPPED-operand form, exp2-domain softmax, software-
// pipelined staging (T3/T14): raw s_barrier + counted vmcnt — tile t+1's
// gload_lds(K) and V register-loads are issued inside tile t's phase and stay
// in flight across the barrier; the next phase's explicit vmcnt(0) lands a
// full compute phase after issue. Ks double-buffered (DMA race); Vt single
// (data flows through regs; barriers order the ds_writes).
//
// mfma(K,Q) -> C[key][q]: lane holds 16 S-values of ONE q -> softmax is
// register-local + 2 shfl. V^T stored key-permuted so each lane's P values
// form its PV B-fragment directly (no LDS round-trip for P).
// l-trick: V^T row 64 = ones -> dt=4 PV MFMA accumulates l = sum(P).
// Defer-max (T13, THR=8): skip O-rescale while tile max is within 8 of the
// running max.
// ---------------------------------------------------------------------------
__global__ __launch_bounds__(256, 4)
void attn_kernel(const unsigned short* __restrict__ qkv,
                 unsigned short* __restrict__ att)
{
    __shared__ alignas(16) unsigned short Ks[2][64][64];  // dbuf (gload_lds dest)
    __shared__ alignas(16) unsigned short Vt[80][80];     // [d][pos]; rows 64..79 const

    const int tid  = threadIdx.x;
    const int lane = tid & 63;
    const int w    = tid >> 6;
    const int b  = blockIdx.z, h = blockIdx.y;
    const int q0 = blockIdx.x * 128;
    const size_t base = (size_t)b * SEQ * QKV_N + (size_t)h * HDIM;

    const int r16 = lane & 15;
    const int g   = lane >> 4;
    const int f7  = r16 & 7;

    // one-time: ones-row (d=64) and zero rows (65..79) of Vt
    if (tid < 80) Vt[64][tid] = 0x3F80;                 // bf16(1.0)
    for (int idx = tid; idx < 15 * 80; idx += 256)
        Vt[65 + idx / 80][idx % 80] = 0;

    // Q fragments (B operand): col=q=r16, elements d = g*8+j (+32)
    short8 qf[2][2];
    #pragma unroll
    for (int mi = 0; mi < 2; ++mi) {
        const unsigned short* qrow =
            qkv + base + (size_t)(q0 + w * 32 + mi * 16 + r16) * QKV_N;
        qf[mi][0] = *(const short8*)(qrow + g * 8);
        qf[mi][1] = *(const short8*)(qrow + 32 + g * 8);
    }

    f32x4 oacc[2][5] = {};          // [mi][dt]: col q=r16, row d=dt*16+g*4+j; dt=4 -> l
    float m_r[2] = { -3e38f, -3e38f };

    // K staging: chunk c covers keys c*8..c*8+7; pre-swizzled source group
    const int krow  = lane >> 3;
    const int kGsrc = (lane & 7) ^ (krow & 7);

    // V staging: lane = key; permuted dest column pos(lane)
    const int k5 = lane & 31, khi = lane >> 5;
    const int vpos = ((k5 < 16) ? ((k5 >> 2) * 8 + (k5 & 3))
                                : (((k5 - 16) >> 2) * 8 + 4 + ((k5 - 16) & 3)))
                     + khi * 32;

    short8 vA0, vA1, vB0, vB1;

    // ---- prologue: issue tile-0 K DMA + V register loads
    #pragma unroll
    for (int c = 0; c < 2; ++c) {
        const int chunk = w * 2 + c;
        gload16(qkv + base + (size_t)(chunk * 8 + krow) * QKV_N + DIM + kGsrc * 8,
                &Ks[0][chunk * 8][0]);
    }
    {
        const unsigned short* vsrc =
            qkv + base + (size_t)lane * QKV_N + 2 * DIM + w * 16;
        vA0 = *(const short8*)(vsrc);
        vA1 = *(const short8*)(vsrc + 8);
    }

#define ATTN_PHASE(TILE, BUF, VC0, VC1, VN0, VN1, DOPRE)                          \
    {                                                                             \
        __builtin_amdgcn_s_barrier();            /* prev compute done (all wv) */ \
        asm volatile("s_waitcnt vmcnt(0)" ::: "memory");  /* K,V of TILE here */  \
        __builtin_amdgcn_sched_barrier(0);                                        \
        _Pragma("unroll")                                                         \
        for (int i = 0; i < 8; ++i) {            /* commit V(TILE) -> Vt */       \
            Vt[w * 16 + i][vpos]     = (unsigned short)VC0[i];                    \
            Vt[w * 16 + 8 + i][vpos] = (unsigned short)VC1[i];                    \
        }                                                                         \
        if (DOPRE) {                              /* issue TILE+64 prefetch */    \
            _Pragma("unroll")                                                     \
            for (int c = 0; c < 2; ++c) {                                         \
                const int chunk = w * 2 + c;                                      \
                gload16(qkv + base +                                              \
                        (size_t)((TILE) + 64 + chunk * 8 + krow) * QKV_N          \
                        + DIM + kGsrc * 8,                                        \
                        &Ks[(BUF) ^ 1][chunk * 8][0]);                            \
            }                                                                     \
            const unsigned short* vsrc = qkv + base +                             \
                (size_t)((TILE) + 64 + lane) * QKV_N + 2 * DIM + w * 16;          \
            VN0 = *(const short8*)(vsrc);                                         \
            VN1 = *(const short8*)(vsrc + 8);                                     \
        }                                                                         \
        asm volatile("s_waitcnt lgkmcnt(0)" ::: "memory");  /* Vt writes done */  \
        __builtin_amdgcn_s_barrier();                                             \
        __builtin_amdgcn_sched_barrier(0);                                        \
        /* ---- compute on Ks[BUF], Vt ---- */                                    \
        f32x4 sacc[2][4] = {};                                                    \
        __builtin_amdgcn_s_setprio(1);                                            \
        _Pragma("unroll")                                                         \
        for (int jt = 0; jt < 4; ++jt) {                                          \
            const int row = jt * 16 + r16;                                        \
            short8 kf0 = *(const short8*)&Ks[BUF][row][(g ^ f7) * 8];             \
            short8 kf1 = *(const short8*)&Ks[BUF][row][((4 + g) ^ f7) * 8];       \
            sacc[0][jt] = MFMA16(kf0, qf[0][0], sacc[0][jt]);                     \
            sacc[0][jt] = MFMA16(kf1, qf[0][1], sacc[0][jt]);                     \
            sacc[1][jt] = MFMA16(kf0, qf[1][0], sacc[1][jt]);                     \
            sacc[1][jt] = MFMA16(kf1, qf[1][1], sacc[1][jt]);                     \
        }                                                                         \
        __builtin_amdgcn_s_setprio(0);                                            \
        short8 pb[2][2];                                                          \
        _Pragma("unroll")                                                         \
        for (int mi = 0; mi < 2; ++mi) {                                          \
            const float a0 = fmaxf(fmaxf(sacc[mi][0][0], sacc[mi][0][1]), sacc[mi][0][2]); \
            const float a1 = fmaxf(fmaxf(sacc[mi][0][3], sacc[mi][1][0]), sacc[mi][1][1]); \
            const float a2 = fmaxf(fmaxf(sacc[mi][1][2], sacc[mi][1][3]), sacc[mi][2][0]); \
            const float a3 = fmaxf(fmaxf(sacc[mi][2][1], sacc[mi][2][2]), sacc[mi][2][3]); \
            const float a4 = fmaxf(fmaxf(sacc[mi][3][0], sacc[mi][3][1]), sacc[mi][3][2]); \
            float tm = fmaxf(fmaxf(fmaxf(a0, a1), a2),                            \
                             fmaxf(fmaxf(a3, a4), sacc[mi][3][3]));               \
            tm = fmaxf(tm, __shfl_xor(tm, 16));                                   \
            tm = fmaxf(tm, __shfl_xor(tm, 32));                                   \
            float nm = m_r[mi];                                                   \
            if (!__all(tm <= m_r[mi] + 8.f)) {    /* T13 defer-max, THR=8 */      \
                nm = fmaxf(m_r[mi], tm);                                          \
                const float f = exp2_fast(m_r[mi] - nm);                          \
                m_r[mi] = nm;                                                     \
                _Pragma("unroll")                                                 \
                for (int dt = 0; dt < 5; ++dt)                                    \
                    _Pragma("unroll")                                             \
                    for (int jr = 0; jr < 4; ++jr)                                \
                        oacc[mi][dt][jr] *= f;                                    \
            }                                                                     \
            unsigned pw[8];                                                       \
            _Pragma("unroll")                                                     \
            for (int jt = 0; jt < 4; ++jt) {                                      \
                const float p0 = exp2_fast(sacc[mi][jt][0] - nm);                 \
                const float p1 = exp2_fast(sacc[mi][jt][1] - nm);                 \
                const float p2 = exp2_fast(sacc[mi][jt][2] - nm);                 \
                const float p3 = exp2_fast(sacc[mi][jt][3] - nm);                 \
                pw[jt * 2]     = cvt_pk_bf16(p0, p1);                             \
                pw[jt * 2 + 1] = cvt_pk_bf16(p2, p3);                             \
            }                                                                     \
            union { unsigned u[4]; short8 s; } c0, c1;                            \
            c0.u[0] = pw[0]; c0.u[1] = pw[1]; c0.u[2] = pw[2]; c0.u[3] = pw[3];   \
            c1.u[0] = pw[4]; c1.u[1] = pw[5]; c1.u[2] = pw[6]; c1.u[3] = pw[7];   \
            pb[mi][0] = c0.s;                                                     \
            pb[mi][1] = c1.s;                                                     \
        }                                                                         \
        __builtin_amdgcn_s_setprio(1);                                            \
        _Pragma("unroll")                                                         \
        for (int dt = 0; dt < 5; ++dt) {          /* dt=4: l via ones-row */      \
            short8 vf0 = *(const short8*)&Vt[dt * 16 + r16][g * 8];               \
            short8 vf1 = *(const short8*)&Vt[dt * 16 + r16][32 + g * 8];          \
            _Pragma("unroll")                                                     \
            for (int mi = 0; mi < 2; ++mi) {                                      \
                oacc[mi][dt] = MFMA16(vf0, pb[mi][0], oacc[mi][dt]);              \
                oacc[mi][dt] = MFMA16(vf1, pb[mi][1], oacc[mi][dt]);              \
            }                                                                     \
        }                                                                         \
        __builtin_amdgcn_s_setprio(0);                                            \
    }

    for (int kt = 0; kt < SEQ; kt += 128) {
        ATTN_PHASE(kt,      0, vA0, vA1, vB0, vB1, true);
        ATTN_PHASE(kt + 64, 1, vB0, vB1, vA0, vA1, (kt + 128 < SEQ));
    }
#undef ATTN_PHASE

    // epilogue: O^T[d][q] -> att[q][h*64+d]; l = oacc[mi][4][0] @ lane q (g=0)
    #pragma unroll
    for (int mi = 0; mi < 2; ++mi) {
        const float inv = 1.f / __shfl(oacc[mi][4][0], r16);
        const int q = q0 + w * 32 + mi * 16 + r16;
        unsigned short* dst = att + (size_t)(b * SEQ + q) * DIM + h * HDIM;
        #pragma unroll
        for (int dt = 0; dt < 4; ++dt)
            #pragma unroll
            for (int jr = 0; jr < 4; ++jr)
                dst[dt * 16 + g * 4 + jr] = f2bf(oacc[mi][dt][jr] * inv);
    }
}

// ---------------------------------------------------------------------------
extern "C" void kernel_launch(void* const* d_in, const int* in_sizes, int n_in,
                              void* d_out, int out_size, void* d_ws, size_t ws_size,
                              hipStream_t stream)
{
    const float* x     = (const float*)d_in[0];
    const float* w_qkv = (const float*)d_in[1];
    const float* w_out = (const float*)d_in[2];
    const float* b_out = (const float*)d_in[3];
    float* out = (float*)d_out;

    unsigned short* qkv   = (unsigned short*)d_ws;      // [8192][3072]
    unsigned short* xb    = qkv + 25165824;             // [8192][1024] (aliased w/ att)
    unsigned short* att   = xb;
    unsigned short* wqkvT = qkv + 33554432;             // [3072][1024]
    unsigned short* woutT = qkv + 36700160;             // [1024][1024]

    conv_kernel<<<dim3(ROWS * DIM / 4 / 256), 256, 0, stream>>>(x, xb, ROWS * DIM / 4);
    convT_kernel<<<dim3(QKV_N / 32, DIM / 32), 256, 0, stream>>>(w_qkv, wqkvT, DIM, QKV_N);
    convT_kernel<<<dim3(DIM / 32, DIM / 32), 256, 0, stream>>>(w_out, woutT, DIM, DIM);

    gemm_kernel<false, true><<<dim3(QKV_N / 128, ROWS / 128), 256, 0, stream>>>(
        xb, wqkvT, nullptr, qkv, ROWS, QKV_N, DIM);

    attn_kernel<<<dim3(SEQ / 128, NHEADS, BATCH), 256, 0, stream>>>(qkv, att);

    gemm_kernel<true, false><<<dim3(DIM / 128, ROWS / 128), 256, 0, stream>>>(
        att, woutT, b_out, out, ROWS, DIM, DIM);
}

// Round 8
// 212.649 us; speedup vs baseline: 1.1192x; 1.1192x over previous
//
#include <hip/hip_runtime.h>
#include <hip/hip_bf16.h>

typedef __attribute__((ext_vector_type(8))) short short8;
typedef __attribute__((ext_vector_type(4))) short short4v;
typedef __attribute__((ext_vector_type(4))) float f32x4;

#define DIM    1024
#define NHEADS 16
#define HDIM   64
#define SEQ    2048
#define BATCH  4
#define ROWS   8192            // BATCH*SEQ
#define QKV_N  3072            // 3*DIM

// 0.125 * log2(e): folds attention scale AND exp->exp2 conversion into Q
#define QSCALE_LOG2E 0.18033688011112042f

__device__ __forceinline__ unsigned short f2bf(float f) {
    union { float f; unsigned u; } v; v.f = f;
    unsigned u = v.u;
    return (unsigned short)((u + 0x7fffu + ((u >> 16) & 1u)) >> 16);   // RNE
}
__device__ __forceinline__ float exp2_fast(float x) {                // v_exp_f32 = 2^x
    float r;
    asm("v_exp_f32 %0, %1" : "=v"(r) : "v"(x));
    return r;
}
// packed f32x2 -> bf16x2 (lo = a, hi = b); no builtin on gfx950 (T12)
__device__ __forceinline__ unsigned cvt_pk_bf16(float a, float b) {
    unsigned r;
    asm("v_cvt_pk_bf16_f32 %0, %1, %2" : "=v"(r) : "v"(a), "v"(b));
    return r;
}

// async global->LDS, 16B per lane; LDS dest = wave-uniform base + lane*16
__device__ __forceinline__ void gload16(const void* g, void* l) {
    __builtin_amdgcn_global_load_lds(
        (const __attribute__((address_space(1))) unsigned int*)g,
        (__attribute__((address_space(3))) unsigned int*)l, 16, 0, 0);
}

#define MFMA16(a, b, c) __builtin_amdgcn_mfma_f32_16x16x32_bf16(a, b, c, 0, 0, 0)

// ---------------------------------------------------------------------------
// convert fp32 -> bf16 (flat)
// ---------------------------------------------------------------------------
__global__ __launch_bounds__(256)
void conv_kernel(const float* __restrict__ src, unsigned short* __restrict__ dst, int n4)
{
    const int i = blockIdx.x * 256 + threadIdx.x;
    if (i >= n4) return;
    const float4 v = ((const float4*)src)[i];
    short4v o;
    o[0] = (short)f2bf(v.x); o[1] = (short)f2bf(v.y);
    o[2] = (short)f2bf(v.z); o[3] = (short)f2bf(v.w);
    ((short4v*)dst)[i] = o;
}

// ---------------------------------------------------------------------------
// transpose + convert: src [R][C] fp32 -> dst [C][R] bf16
// ---------------------------------------------------------------------------
__global__ __launch_bounds__(256)
void convT_kernel(const float* __restrict__ src, unsigned short* __restrict__ dst,
                  int R, int C)
{
    __shared__ float T[32][33];
    const int r0 = blockIdx.y * 32, c0 = blockIdx.x * 32;
    const int tc = threadIdx.x & 31, tr = threadIdx.x >> 5;   // 32 x 8
    #pragma unroll
    for (int i = 0; i < 4; ++i)
        T[tr + i * 8][tc] = src[(size_t)(r0 + tr + i * 8) * C + c0 + tc];
    __syncthreads();
    #pragma unroll
    for (int i = 0; i < 4; ++i)
        dst[(size_t)(c0 + tr + i * 8) * R + r0 + tc] = f2bf(T[tc][tr + i * 8]);
}

// ---------------------------------------------------------------------------
// bf16 MFMA GEMM (m97 structure): C[M,N] = A[M,K] @ BT[N,K]^T (+bias).
// 128x128 tile, BK=32, 256 thr = 4 waves (2x2), 4x4 16x16x32 frags per wave.
// QSCALE: multiply cols < DIM (the Q third of qkv) by 0.125*log2e.
// ---------------------------------------------------------------------------
template<bool WITH_BIAS, bool QSCALE>
__global__ __launch_bounds__(256)
void gemm_kernel(const unsigned short* __restrict__ A,   // [M][K] bf16
                 const unsigned short* __restrict__ BT,  // [N][K] bf16
                 const float* __restrict__ bias,
                 void* __restrict__ Cp, int M, int N, int K)
{
    __shared__ alignas(16) unsigned short LA[128][32];
    __shared__ alignas(16) unsigned short LB[128][32];

    const int tid  = threadIdx.x;
    const int lane = tid & 63;
    const int w    = tid >> 6;
    const int wr   = w >> 1, wc = w & 1;
    const int bm   = blockIdx.y * 128, bn = blockIdx.x * 128;
    const int r16  = lane & 15, g = lane >> 4;

    f32x4 acc[4][4] = {};

    const int srow = lane >> 2, skg = (lane & 3) * 8;

    for (int k0 = 0; k0 < K; k0 += 32) {
        #pragma unroll
        for (int c = 0; c < 2; ++c) {
            const int chunk = w * 2 + c;            // 8 chunks over 4 waves
            gload16(A  + (size_t)(bm + chunk * 16 + srow) * K + k0 + skg, &LA[chunk * 16][0]);
            gload16(BT + (size_t)(bn + chunk * 16 + srow) * K + k0 + skg, &LB[chunk * 16][0]);
        }
        __syncthreads();
        short8 af[4], bf_[4];
        #pragma unroll
        for (int i = 0; i < 4; ++i) {
            af[i]  = *(const short8*)&LA[wr * 64 + i * 16 + r16][g * 8];
            bf_[i] = *(const short8*)&LB[wc * 64 + i * 16 + r16][g * 8];
        }
        __builtin_amdgcn_s_setprio(1);
        #pragma unroll
        for (int mi = 0; mi < 4; ++mi)
            #pragma unroll
            for (int ni = 0; ni < 4; ++ni)
                acc[mi][ni] = MFMA16(af[mi], bf_[ni], acc[mi][ni]);
        __builtin_amdgcn_s_setprio(0);
        __syncthreads();
    }

    #pragma unroll
    for (int mi = 0; mi < 4; ++mi)
        #pragma unroll
        for (int ni = 0; ni < 4; ++ni) {
            const int gcol = bn + wc * 64 + ni * 16 + r16;
            #pragma unroll
            for (int j = 0; j < 4; ++j) {
                const int grow = bm + wr * 64 + mi * 16 + g * 4 + j;
                float v = acc[mi][ni][j];
                if (QSCALE && gcol < DIM) v *= QSCALE_LOG2E;
                if (WITH_BIAS)
                    ((float*)Cp)[(size_t)grow * N + gcol] = v + bias[gcol];
                else
                    ((unsigned short*)Cp)[(size_t)grow * N + gcol] = f2bf(v);
            }
        }
}

// ---------------------------------------------------------------------------
// MFMA flash attention, SWAPPED-operand form, exp2-domain softmax.
// Pipelined v2 (single body, no cross-iteration V regs — the round-7 spill
// lesson): Ks double-buffered via gload_lds issued ONE TILE AHEAD; the only
// manually-synced hazard is DMA->ds_read (compiler can't see DMA writes):
// one counted vmcnt + barrier per tile. Steady queue at the wait:
// [K(t)x2 oldest, V(t)x2, K(t+1)x2] -> vmcnt(4) drains exactly K(t);
// last tile: vmcnt(2). V goes global->reg at loop top and is committed to
// Vt AFTER QK+softmax (T14 issue-early/write-late): its latency hides under
// compute, regs live only within the iteration.
//
// mfma(K,Q) -> C[key][q]: lane holds 16 S-values of ONE q -> softmax is
// register-local + 2 shfl. V^T stored key-permuted so each lane's P values
// form its PV B-fragment directly. l-trick: Vt row 64 = ones -> dt=4 PV
// MFMA accumulates l = sum(P). Defer-max (T13, THR=8).
// ---------------------------------------------------------------------------
__global__ __launch_bounds__(256, 4)
void attn_kernel(const unsigned short* __restrict__ qkv,
                 unsigned short* __restrict__ att)
{
    __shared__ alignas(16) unsigned short Ks[2][64][64];  // dbuf (gload_lds dest)
    __shared__ alignas(16) unsigned short Vt[80][80];     // [d][pos]; rows 64..79 const

    const int tid  = threadIdx.x;
    const int lane = tid & 63;
    const int w    = tid >> 6;
    const int b  = blockIdx.z, h = blockIdx.y;
    const int q0 = blockIdx.x * 128;
    const size_t base = (size_t)b * SEQ * QKV_N + (size_t)h * HDIM;

    const int r16 = lane & 15;
    const int g   = lane >> 4;
    const int f7  = r16 & 7;

    // one-time: ones-row (d=64) and zero rows (65..79) of Vt
    if (tid < 80) Vt[64][tid] = 0x3F80;                 // bf16(1.0)
    for (int idx = tid; idx < 15 * 80; idx += 256)
        Vt[65 + idx / 80][idx % 80] = 0;
    __syncthreads();    // init visible before first use (nothing else in flight)

    // K staging: chunk c covers keys c*8..c*8+7; pre-swizzled source group
    const int krow  = lane >> 3;
    const int kGsrc = (lane & 7) ^ (krow & 7);

    // prologue: issue K(0) DMA
    #pragma unroll
    for (int c = 0; c < 2; ++c) {
        const int chunk = w * 2 + c;
        gload16(qkv + base + (size_t)(chunk * 8 + krow) * QKV_N + DIM + kGsrc * 8,
                &Ks[0][chunk * 8][0]);
    }

    // Q fragments (B operand): col=q=r16, elements d = g*8+j (+32)
    short8 qf[2][2];
    #pragma unroll
    for (int mi = 0; mi < 2; ++mi) {
        const unsigned short* qrow =
            qkv + base + (size_t)(q0 + w * 32 + mi * 16 + r16) * QKV_N;
        qf[mi][0] = *(const short8*)(qrow + g * 8);
        qf[mi][1] = *(const short8*)(qrow + 32 + g * 8);
    }

    f32x4 oacc[2][5] = {};          // [mi][dt]: col q=r16, row d=dt*16+g*4+j; dt=4 -> l
    float m_r[2] = { -3e38f, -3e38f };

    // V staging: lane = key; permuted dest column pos(lane)
    const int k5 = lane & 31, khi = lane >> 5;
    const int vpos = ((k5 < 16) ? ((k5 >> 2) * 8 + (k5 & 3))
                                : (((k5 - 16) >> 2) * 8 + 4 + ((k5 - 16) & 3)))
                     + khi * 32;

    for (int kt = 0; kt < SEQ; kt += 64) {
        const int buf = (kt >> 6) & 1;

        // --- issue V(t) register loads (committed after QK: latency hides)
        const unsigned short* vsrc =
            qkv + base + (size_t)(kt + lane) * QKV_N + 2 * DIM + w * 16;
        short8 v0 = *(const short8*)(vsrc);
        short8 v1 = *(const short8*)(vsrc + 8);

        // --- issue K(t+1) DMA into the other buffer; counted wait for K(t)
        if (kt + 64 < SEQ) {
            #pragma unroll
            for (int c = 0; c < 2; ++c) {
                const int chunk = w * 2 + c;
                gload16(qkv + base + (size_t)(kt + 64 + chunk * 8 + krow) * QKV_N
                        + DIM + kGsrc * 8,
                        &Ks[buf ^ 1][chunk * 8][0]);
            }
            asm volatile("s_waitcnt vmcnt(4)" ::: "memory");   // drain K(t) only
        } else {
            asm volatile("s_waitcnt vmcnt(2)" ::: "memory");   // drain K(t) only
        }
        __builtin_amdgcn_s_barrier();          // all waves' K(t) landed; Vt free
        __builtin_amdgcn_sched_barrier(0);

        // --- S^T = K Q^T : C[key][q]  (exp2 domain)
        f32x4 sacc[2][4] = {};
        __builtin_amdgcn_s_setprio(1);
        #pragma unroll
        for (int jt = 0; jt < 4; ++jt) {
            const int row = jt * 16 + r16;
            short8 kf0 = *(const short8*)&Ks[buf][row][(g ^ f7) * 8];
            short8 kf1 = *(const short8*)&Ks[buf][row][((4 + g) ^ f7) * 8];
            sacc[0][jt] = MFMA16(kf0, qf[0][0], sacc[0][jt]);
            sacc[0][jt] = MFMA16(kf1, qf[0][1], sacc[0][jt]);
            sacc[1][jt] = MFMA16(kf0, qf[1][0], sacc[1][jt]);
            sacc[1][jt] = MFMA16(kf1, qf[1][1], sacc[1][jt]);
        }
        __builtin_amdgcn_s_setprio(0);

        // --- softmax (register-local rows, exp2 domain) + lane-local P frags
        short8 pb[2][2];
        #pragma unroll
        for (int mi = 0; mi < 2; ++mi) {
            const float a0 = fmaxf(fmaxf(sacc[mi][0][0], sacc[mi][0][1]), sacc[mi][0][2]);
            const float a1 = fmaxf(fmaxf(sacc[mi][0][3], sacc[mi][1][0]), sacc[mi][1][1]);
            const float a2 = fmaxf(fmaxf(sacc[mi][1][2], sacc[mi][1][3]), sacc[mi][2][0]);
            const float a3 = fmaxf(fmaxf(sacc[mi][2][1], sacc[mi][2][2]), sacc[mi][2][3]);
            const float a4 = fmaxf(fmaxf(sacc[mi][3][0], sacc[mi][3][1]), sacc[mi][3][2]);
            float tm = fmaxf(fmaxf(fmaxf(a0, a1), a2),
                             fmaxf(fmaxf(a3, a4), sacc[mi][3][3]));
            tm = fmaxf(tm, __shfl_xor(tm, 16));
            tm = fmaxf(tm, __shfl_xor(tm, 32));

            float nm = m_r[mi];
            if (!__all(tm <= m_r[mi] + 8.f)) {       // T13 defer-max, THR=8
                nm = fmaxf(m_r[mi], tm);
                const float f = exp2_fast(m_r[mi] - nm);
                m_r[mi] = nm;
                #pragma unroll
                for (int dt = 0; dt < 5; ++dt)       // includes the l-row
                    #pragma unroll
                    for (int jr = 0; jr < 4; ++jr)
                        oacc[mi][dt][jr] *= f;
            }

            unsigned pw[8];
            #pragma unroll
            for (int jt = 0; jt < 4; ++jt) {
                const float p0 = exp2_fast(sacc[mi][jt][0] - nm);
                const float p1 = exp2_fast(sacc[mi][jt][1] - nm);
                const float p2 = exp2_fast(sacc[mi][jt][2] - nm);
                const float p3 = exp2_fast(sacc[mi][jt][3] - nm);
                pw[jt * 2]     = cvt_pk_bf16(p0, p1);
                pw[jt * 2 + 1] = cvt_pk_bf16(p2, p3);
            }

            union { unsigned u[4]; short8 s; } c0, c1;
            c0.u[0] = pw[0]; c0.u[1] = pw[1]; c0.u[2] = pw[2]; c0.u[3] = pw[3];
            c1.u[0] = pw[4]; c1.u[1] = pw[5]; c1.u[2] = pw[6]; c1.u[7 - 7] = c1.u[0];
            c1.u[0] = pw[4]; c1.u[1] = pw[5]; c1.u[2] = pw[6]; c1.u[3] = pw[7];
            pb[mi][0] = c0.s;   // keys (perm. positions) 0..31
            pb[mi][1] = c1.s;   // keys 32..63
        }

        // --- commit V(t) regs -> Vt (compiler auto-waits the V loads)
        #pragma unroll
        for (int i = 0; i < 8; ++i) {
            Vt[w * 16 + i][vpos]     = (unsigned short)v0[i];
            Vt[w * 16 + 8 + i][vpos] = (unsigned short)v1[i];
        }
        asm volatile("s_waitcnt lgkmcnt(0)" ::: "memory");
        __builtin_amdgcn_s_barrier();          // Vt(t) visible to all waves
        __builtin_amdgcn_sched_barrier(0);

        // --- O^T += V^T P^T (dt=4 accumulates l via the ones-row)
        __builtin_amdgcn_s_setprio(1);
        #pragma unroll
        for (int dt = 0; dt < 5; ++dt) {
            short8 vf0 = *(const short8*)&Vt[dt * 16 + r16][g * 8];
            short8 vf1 = *(const short8*)&Vt[dt * 16 + r16][32 + g * 8];
            #pragma unroll
            for (int mi = 0; mi < 2; ++mi) {
                oacc[mi][dt] = MFMA16(vf0, pb[mi][0], oacc[mi][dt]);
                oacc[mi][dt] = MFMA16(vf1, pb[mi][1], oacc[mi][dt]);
            }
        }
        __builtin_amdgcn_s_setprio(0);
    }

    // epilogue: O^T[d][q] -> att[q][h*64+d]; l = oacc[mi][4][0] @ lane q (g=0)
    #pragma unroll
    for (int mi = 0; mi < 2; ++mi) {
        const float inv = 1.f / __shfl(oacc[mi][4][0], r16);
        const int q = q0 + w * 32 + mi * 16 + r16;
        unsigned short* dst = att + (size_t)(b * SEQ + q) * DIM + h * HDIM;
        #pragma unroll
        for (int dt = 0; dt < 4; ++dt)
            #pragma unroll
            for (int jr = 0; jr < 4; ++jr)
                dst[dt * 16 + g * 4 + jr] = f2bf(oacc[mi][dt][jr] * inv);
    }
}

// ---------------------------------------------------------------------------
extern "C" void kernel_launch(void* const* d_in, const int* in_sizes, int n_in,
                              void* d_out, int out_size, void* d_ws, size_t ws_size,
                              hipStream_t stream)
{
    const float* x     = (const float*)d_in[0];
    const float* w_qkv = (const float*)d_in[1];
    const float* w_out = (const float*)d_in[2];
    const float* b_out = (const float*)d_in[3];
    float* out = (float*)d_out;

    unsigned short* qkv   = (unsigned short*)d_ws;      // [8192][3072]
    unsigned short* xb    = qkv + 25165824;             // [8192][1024] (aliased w/ att)
    unsigned short* att   = xb;
    unsigned short* wqkvT = qkv + 33554432;             // [3072][1024]
    unsigned short* woutT = qkv + 36700160;             // [1024][1024]

    conv_kernel<<<dim3(ROWS * DIM / 4 / 256), 256, 0, stream>>>(x, xb, ROWS * DIM / 4);
    convT_kernel<<<dim3(QKV_N / 32, DIM / 32), 256, 0, stream>>>(w_qkv, wqkvT, DIM, QKV_N);
    convT_kernel<<<dim3(DIM / 32, DIM / 32), 256, 0, stream>>>(w_out, woutT, DIM, DIM);

    gemm_kernel<false, true><<<dim3(QKV_N / 128, ROWS / 128), 256, 0, stream>>>(
        xb, wqkvT, nullptr, qkv, ROWS, QKV_N, DIM);

    attn_kernel<<<dim3(SEQ / 128, NHEADS, BATCH), 256, 0, stream>>>(qkv, att);

    gemm_kernel<true, false><<<dim3(DIM / 128, ROWS / 128), 256, 0, stream>>>(
        att, woutT, b_out, out, ROWS, DIM, DIM);
}

// Round 9
// 210.907 us; speedup vs baseline: 1.1285x; 1.0083x over previous
//
#include <hip/hip_runtime.h>
#include <hip/hip_bf16.h>

typedef __attribute__((ext_vector_type(8))) short short8;
typedef __attribute__((ext_vector_type(4))) short short4v;
typedef __attribute__((ext_vector_type(4))) float f32x4;

#define DIM    1024
#define NHEADS 16
#define HDIM   64
#define SEQ    2048
#define BATCH  4
#define ROWS   8192            // BATCH*SEQ
#define QKV_N  3072            // 3*DIM

// 0.125 * log2(e): folds attention scale AND exp->exp2 conversion into Q
#define QSCALE_LOG2E 0.18033688011112042f

__device__ __forceinline__ unsigned short f2bf(float f) {
    union { float f; unsigned u; } v; v.f = f;
    unsigned u = v.u;
    return (unsigned short)((u + 0x7fffu + ((u >> 16) & 1u)) >> 16);   // RNE
}
__device__ __forceinline__ float exp2_fast(float x) {                // v_exp_f32 = 2^x
    float r;
    asm("v_exp_f32 %0, %1" : "=v"(r) : "v"(x));
    return r;
}
// packed f32x2 -> bf16x2 (lo = a, hi = b); no builtin on gfx950 (T12)
__device__ __forceinline__ unsigned cvt_pk_bf16(float a, float b) {
    unsigned r;
    asm("v_cvt_pk_bf16_f32 %0, %1, %2" : "=v"(r) : "v"(a), "v"(b));
    return r;
}

// async global->LDS, 16B per lane; LDS dest = wave-uniform base + lane*16
__device__ __forceinline__ void gload16(const void* g, void* l) {
    __builtin_amdgcn_global_load_lds(
        (const __attribute__((address_space(1))) unsigned int*)g,
        (__attribute__((address_space(3))) unsigned int*)l, 16, 0, 0);
}

#define MFMA16(a, b, c) __builtin_amdgcn_mfma_f32_16x16x32_bf16(a, b, c, 0, 0, 0)

// ---------------------------------------------------------------------------
// convert fp32 -> bf16 (flat)
// ---------------------------------------------------------------------------
__global__ __launch_bounds__(256)
void conv_kernel(const float* __restrict__ src, unsigned short* __restrict__ dst, int n4)
{
    const int i = blockIdx.x * 256 + threadIdx.x;
    if (i >= n4) return;
    const float4 v = ((const float4*)src)[i];
    short4v o;
    o[0] = (short)f2bf(v.x); o[1] = (short)f2bf(v.y);
    o[2] = (short)f2bf(v.z); o[3] = (short)f2bf(v.w);
    ((short4v*)dst)[i] = o;
}

// ---------------------------------------------------------------------------
// transpose + convert: src [R][C] fp32 -> dst [C][R] bf16
// ---------------------------------------------------------------------------
__global__ __launch_bounds__(256)
void convT_kernel(const float* __restrict__ src, unsigned short* __restrict__ dst,
                  int R, int C)
{
    __shared__ float T[32][33];
    const int r0 = blockIdx.y * 32, c0 = blockIdx.x * 32;
    const int tc = threadIdx.x & 31, tr = threadIdx.x >> 5;   // 32 x 8
    #pragma unroll
    for (int i = 0; i < 4; ++i)
        T[tr + i * 8][tc] = src[(size_t)(r0 + tr + i * 8) * C + c0 + tc];
    __syncthreads();
    #pragma unroll
    for (int i = 0; i < 4; ++i)
        dst[(size_t)(c0 + tr + i * 8) * R + r0 + tc] = f2bf(T[tc][tr + i * 8]);
}

// ---------------------------------------------------------------------------
// bf16 MFMA GEMM (m97 structure): C[M,N] = A[M,K] @ BT[N,K]^T (+bias).
// 128x128 tile, BK=32, 256 thr = 4 waves (2x2), 4x4 16x16x32 frags per wave.
// QSCALE: multiply cols < DIM (the Q third of qkv) by 0.125*log2e.
// ---------------------------------------------------------------------------
template<bool WITH_BIAS, bool QSCALE>
__global__ __launch_bounds__(256)
void gemm_kernel(const unsigned short* __restrict__ A,   // [M][K] bf16
                 const unsigned short* __restrict__ BT,  // [N][K] bf16
                 const float* __restrict__ bias,
                 void* __restrict__ Cp, int M, int N, int K)
{
    __shared__ alignas(16) unsigned short LA[128][32];
    __shared__ alignas(16) unsigned short LB[128][32];

    const int tid  = threadIdx.x;
    const int lane = tid & 63;
    const int w    = tid >> 6;
    const int wr   = w >> 1, wc = w & 1;
    const int bm   = blockIdx.y * 128, bn = blockIdx.x * 128;
    const int r16  = lane & 15, g = lane >> 4;

    f32x4 acc[4][4] = {};

    const int srow = lane >> 2, skg = (lane & 3) * 8;

    for (int k0 = 0; k0 < K; k0 += 32) {
        #pragma unroll
        for (int c = 0; c < 2; ++c) {
            const int chunk = w * 2 + c;            // 8 chunks over 4 waves
            gload16(A  + (size_t)(bm + chunk * 16 + srow) * K + k0 + skg, &LA[chunk * 16][0]);
            gload16(BT + (size_t)(bn + chunk * 16 + srow) * K + k0 + skg, &LB[chunk * 16][0]);
        }
        __syncthreads();
        short8 af[4], bf_[4];
        #pragma unroll
        for (int i = 0; i < 4; ++i) {
            af[i]  = *(const short8*)&LA[wr * 64 + i * 16 + r16][g * 8];
            bf_[i] = *(const short8*)&LB[wc * 64 + i * 16 + r16][g * 8];
        }
        __builtin_amdgcn_s_setprio(1);
        #pragma unroll
        for (int mi = 0; mi < 4; ++mi)
            #pragma unroll
            for (int ni = 0; ni < 4; ++ni)
                acc[mi][ni] = MFMA16(af[mi], bf_[ni], acc[mi][ni]);
        __builtin_amdgcn_s_setprio(0);
        __syncthreads();
    }

    #pragma unroll
    for (int mi = 0; mi < 4; ++mi)
        #pragma unroll
        for (int ni = 0; ni < 4; ++ni) {
            const int gcol = bn + wc * 64 + ni * 16 + r16;
            #pragma unroll
            for (int j = 0; j < 4; ++j) {
                const int grow = bm + wr * 64 + mi * 16 + g * 4 + j;
                float v = acc[mi][ni][j];
                if (QSCALE && gcol < DIM) v *= QSCALE_LOG2E;
                if (WITH_BIAS)
                    ((float*)Cp)[(size_t)grow * N + gcol] = v + bias[gcol];
                else
                    ((unsigned short*)Cp)[(size_t)grow * N + gcol] = f2bf(v);
            }
        }
}

// ---------------------------------------------------------------------------
// MFMA flash attention, SWAPPED-operand form, exp2-domain softmax.
// SINGLE-BARRIER pipeline (round-9): Ks AND Vd both double-buffered; the
// constant ones/zeros block (Vones) lives outside the buffers. Per tile:
//   [vmcnt(0)+lgkm(0); s_barrier]   <- K(t) landed + V(t) committed, all waves
//   prefetch V(t+1)->regs; issue K(t+1) DMA -> Ks[buf^1]
//   QK(t) ; softmax(t)
//   commit V(t+1) -> Vd[buf^1]      <- auto vmcnt(2): K-DMA stays in flight
//   PV(t) from Vd[buf] + Vones
// Both K and V get a full tile of prefetch distance; barrier count halved.
//
// mfma(K,Q) -> C[key][q]: lane holds 16 S-values of ONE q -> softmax is
// register-local + 2 shfl. V^T stored key-permuted so each lane's P values
// form its PV B-fragment directly. l-trick: Vones row 0 = ones -> dt=4 PV
// MFMA accumulates l = sum(P). Defer-max (T13, THR=8).
// ---------------------------------------------------------------------------
__global__ __launch_bounds__(256, 4)
void attn_kernel(const unsigned short* __restrict__ qkv,
                 unsigned short* __restrict__ att)
{
    __shared__ alignas(16) unsigned short Ks[2][64][64];   // dbuf (gload_lds dest)
    __shared__ alignas(16) unsigned short Vd[2][64][80];   // dbuf [d][pos] (permuted)
    __shared__ alignas(16) unsigned short Vones[16][80];   // row0 = 1.0, rest 0

    const int tid  = threadIdx.x;
    const int lane = tid & 63;
    const int w    = tid >> 6;
    const int b  = blockIdx.z, h = blockIdx.y;
    const int q0 = blockIdx.x * 128;
    const size_t base = (size_t)b * SEQ * QKV_N + (size_t)h * HDIM;

    const int r16 = lane & 15;
    const int g   = lane >> 4;
    const int f7  = r16 & 7;

    // init Vones (row 0 ones, rows 1..15 zero)
    for (int idx = tid; idx < 16 * 80; idx += 256)
        Vones[idx / 80][idx % 80] = (idx < 80) ? 0x3F80 : 0;

    // K staging: chunk c covers keys c*8..c*8+7; pre-swizzled source group
    const int krow  = lane >> 3;
    const int kGsrc = (lane & 7) ^ (krow & 7);

    // V staging: lane = key; permuted dest column pos(lane)
    const int k5 = lane & 31, khi = lane >> 5;
    const int vpos = ((k5 < 16) ? ((k5 >> 2) * 8 + (k5 & 3))
                                : (((k5 - 16) >> 2) * 8 + 4 + ((k5 - 16) & 3)))
                     + khi * 32;

    // ---- prologue: V(0) -> regs, K(0) DMA, Q frags, commit V(0)
    short8 pv0, pv1;
    {
        const unsigned short* vsrc =
            qkv + base + (size_t)lane * QKV_N + 2 * DIM + w * 16;
        pv0 = *(const short8*)(vsrc);
        pv1 = *(const short8*)(vsrc + 8);
    }
    #pragma unroll
    for (int c = 0; c < 2; ++c) {
        const int chunk = w * 2 + c;
        gload16(qkv + base + (size_t)(chunk * 8 + krow) * QKV_N + DIM + kGsrc * 8,
                &Ks[0][chunk * 8][0]);
    }

    // Q fragments (B operand): col=q=r16, elements d = g*8+j (+32)
    short8 qf[2][2];
    #pragma unroll
    for (int mi = 0; mi < 2; ++mi) {
        const unsigned short* qrow =
            qkv + base + (size_t)(q0 + w * 32 + mi * 16 + r16) * QKV_N;
        qf[mi][0] = *(const short8*)(qrow + g * 8);
        qf[mi][1] = *(const short8*)(qrow + 32 + g * 8);
    }

    {   // commit V(0) -> Vd[0] (compiler auto-waits just the V loads)
        #pragma unroll
        for (int i = 0; i < 8; ++i) {
            Vd[0][w * 16 + i][vpos]     = (unsigned short)pv0[i];
            Vd[0][w * 16 + 8 + i][vpos] = (unsigned short)pv1[i];
        }
    }

    f32x4 oacc[2][5] = {};          // [mi][dt]: col q=r16, row d=dt*16+g*4+j; dt=4 -> l
    float m_r[2] = { -3e38f, -3e38f };

    for (int kt = 0; kt < SEQ; kt += 64) {
        const int buf = (kt >> 6) & 1;
        const bool pre = (kt + 64 < SEQ);

        // ---- the single barrier: K(t) landed, V(t) committed (all waves)
        asm volatile("s_waitcnt vmcnt(0) lgkmcnt(0)" ::: "memory");
        __builtin_amdgcn_s_barrier();
        __builtin_amdgcn_sched_barrier(0);

        // ---- prefetch tile t+1: V loads FIRST, then K DMA (so the V commit
        //      later waits vmcnt(2) and leaves the K-DMA in flight)
        short8 nv0, nv1;
        if (pre) {
            const unsigned short* vsrc =
                qkv + base + (size_t)(kt + 64 + lane) * QKV_N + 2 * DIM + w * 16;
            nv0 = *(const short8*)(vsrc);
            nv1 = *(const short8*)(vsrc + 8);
            #pragma unroll
            for (int c = 0; c < 2; ++c) {
                const int chunk = w * 2 + c;
                gload16(qkv + base + (size_t)(kt + 64 + chunk * 8 + krow) * QKV_N
                        + DIM + kGsrc * 8,
                        &Ks[buf ^ 1][chunk * 8][0]);
            }
        }

        // ---- S^T = K Q^T : C[key][q]  (exp2 domain)
        f32x4 sacc[2][4] = {};
        __builtin_amdgcn_s_setprio(1);
        #pragma unroll
        for (int jt = 0; jt < 4; ++jt) {
            const int row = jt * 16 + r16;
            short8 kf0 = *(const short8*)&Ks[buf][row][(g ^ f7) * 8];
            short8 kf1 = *(const short8*)&Ks[buf][row][((4 + g) ^ f7) * 8];
            sacc[0][jt] = MFMA16(kf0, qf[0][0], sacc[0][jt]);
            sacc[0][jt] = MFMA16(kf1, qf[0][1], sacc[0][jt]);
            sacc[1][jt] = MFMA16(kf0, qf[1][0], sacc[1][jt]);
            sacc[1][jt] = MFMA16(kf1, qf[1][1], sacc[1][jt]);
        }
        __builtin_amdgcn_s_setprio(0);

        // ---- softmax (register-local rows, exp2 domain) + lane-local P frags
        short8 pb[2][2];
        #pragma unroll
        for (int mi = 0; mi < 2; ++mi) {
            const float a0 = fmaxf(fmaxf(sacc[mi][0][0], sacc[mi][0][1]), sacc[mi][0][2]);
            const float a1 = fmaxf(fmaxf(sacc[mi][0][3], sacc[mi][1][0]), sacc[mi][1][1]);
            const float a2 = fmaxf(fmaxf(sacc[mi][1][2], sacc[mi][1][3]), sacc[mi][2][0]);
            const float a3 = fmaxf(fmaxf(sacc[mi][2][1], sacc[mi][2][2]), sacc[mi][2][3]);
            const float a4 = fmaxf(fmaxf(sacc[mi][3][0], sacc[mi][3][1]), sacc[mi][3][2]);
            float tm = fmaxf(fmaxf(fmaxf(a0, a1), a2),
                             fmaxf(fmaxf(a3, a4), sacc[mi][3][3]));
            tm = fmaxf(tm, __shfl_xor(tm, 16));
            tm = fmaxf(tm, __shfl_xor(tm, 32));

            float nm = m_r[mi];
            if (!__all(tm <= m_r[mi] + 8.f)) {       // T13 defer-max, THR=8
                nm = fmaxf(m_r[mi], tm);
                const float f = exp2_fast(m_r[mi] - nm);
                m_r[mi] = nm;
                #pragma unroll
                for (int dt = 0; dt < 5; ++dt)       // includes the l-row
                    #pragma unroll
                    for (int jr = 0; jr < 4; ++jr)
                        oacc[mi][dt][jr] *= f;
            }

            unsigned pw[8];
            #pragma unroll
            for (int jt = 0; jt < 4; ++jt) {
                const float p0 = exp2_fast(sacc[mi][jt][0] - nm);
                const float p1 = exp2_fast(sacc[mi][jt][1] - nm);
                const float p2 = exp2_fast(sacc[mi][jt][2] - nm);
                const float p3 = exp2_fast(sacc[mi][jt][3] - nm);
                pw[jt * 2]     = cvt_pk_bf16(p0, p1);
                pw[jt * 2 + 1] = cvt_pk_bf16(p2, p3);
            }

            union { unsigned u[4]; short8 s; } c0, c1;
            c0.u[0] = pw[0]; c0.u[1] = pw[1]; c0.u[2] = pw[2]; c0.u[3] = pw[3];
            c1.u[0] = pw[4]; c1.u[1] = pw[5]; c1.u[2] = pw[6]; c1.u[3] = pw[7];
            pb[mi][0] = c0.s;   // keys (perm. positions) 0..31
            pb[mi][1] = c1.s;   // keys 32..63
        }

        // ---- commit V(t+1) -> Vd[buf^1] (K(t+1) DMA stays outstanding)
        if (pre) {
            #pragma unroll
            for (int i = 0; i < 8; ++i) {
                Vd[buf ^ 1][w * 16 + i][vpos]     = (unsigned short)nv0[i];
                Vd[buf ^ 1][w * 16 + 8 + i][vpos] = (unsigned short)nv1[i];
            }
        }

        // ---- O^T += V^T P^T : dt 0..3 from Vd[buf], dt=4 (l) from Vones
        __builtin_amdgcn_s_setprio(1);
        #pragma unroll
        for (int dt = 0; dt < 4; ++dt) {
            short8 vf0 = *(const short8*)&Vd[buf][dt * 16 + r16][g * 8];
            short8 vf1 = *(const short8*)&Vd[buf][dt * 16 + r16][32 + g * 8];
            #pragma unroll
            for (int mi = 0; mi < 2; ++mi) {
                oacc[mi][dt] = MFMA16(vf0, pb[mi][0], oacc[mi][dt]);
                oacc[mi][dt] = MFMA16(vf1, pb[mi][1], oacc[mi][dt]);
            }
        }
        {
            short8 vf0 = *(const short8*)&Vones[r16][g * 8];
            short8 vf1 = *(const short8*)&Vones[r16][32 + g * 8];
            #pragma unroll
            for (int mi = 0; mi < 2; ++mi) {
                oacc[mi][4] = MFMA16(vf0, pb[mi][0], oacc[mi][4]);
                oacc[mi][4] = MFMA16(vf1, pb[mi][1], oacc[mi][4]);
            }
        }
        __builtin_amdgcn_s_setprio(0);
    }

    // epilogue: O^T[d][q] -> att[q][h*64+d]; l = oacc[mi][4][0] @ lane q (g=0)
    #pragma unroll
    for (int mi = 0; mi < 2; ++mi) {
        const float inv = 1.f / __shfl(oacc[mi][4][0], r16);
        const int q = q0 + w * 32 + mi * 16 + r16;
        unsigned short* dst = att + (size_t)(b * SEQ + q) * DIM + h * HDIM;
        #pragma unroll
        for (int dt = 0; dt < 4; ++dt)
            #pragma unroll
            for (int jr = 0; jr < 4; ++jr)
                dst[dt * 16 + g * 4 + jr] = f2bf(oacc[mi][dt][jr] * inv);
    }
}

// ---------------------------------------------------------------------------
extern "C" void kernel_launch(void* const* d_in, const int* in_sizes, int n_in,
                              void* d_out, int out_size, void* d_ws, size_t ws_size,
                              hipStream_t stream)
{
    const float* x     = (const float*)d_in[0];
    const float* w_qkv = (const float*)d_in[1];
    const float* w_out = (const float*)d_in[2];
    const float* b_out = (const float*)d_in[3];
    float* out = (float*)d_out;

    unsigned short* qkv   = (unsigned short*)d_ws;      // [8192][3072]
    unsigned short* xb    = qkv + 25165824;             // [8192][1024] (aliased w/ att)
    unsigned short* att   = xb;
    unsigned short* wqkvT = qkv + 33554432;             // [3072][1024]
    unsigned short* woutT = qkv + 36700160;             // [1024][1024]

    conv_kernel<<<dim3(ROWS * DIM / 4 / 256), 256, 0, stream>>>(x, xb, ROWS * DIM / 4);
    convT_kernel<<<dim3(QKV_N / 32, DIM / 32), 256, 0, stream>>>(w_qkv, wqkvT, DIM, QKV_N);
    convT_kernel<<<dim3(DIM / 32, DIM / 32), 256, 0, stream>>>(w_out, woutT, DIM, DIM);

    gemm_kernel<false, true><<<dim3(QKV_N / 128, ROWS / 128), 256, 0, stream>>>(
        xb, wqkvT, nullptr, qkv, ROWS, QKV_N, DIM);

    attn_kernel<<<dim3(SEQ / 128, NHEADS, BATCH), 256, 0, stream>>>(qkv, att);

    gemm_kernel<true, false><<<dim3(DIM / 128, ROWS / 128), 256, 0, stream>>>(
        att, woutT, b_out, out, ROWS, DIM, DIM);
}